// Round 1
// baseline (220.845 us; speedup 1.0000x reference)
//
#include <hip/hip_runtime.h>

// Sizes (fixed by the problem)
#define BB 32
#define MM 128
#define PP 20
#define AA 32
#define TT 32
#define HH 32
#define EE 64

// ---------------------------------------------------------------------------
// Local graph: per group (b,m), run 2-layer MLP+LN+ReLU over P points of IN
// dims, then per-channel max over points; write duplicated into 64 channels.
// Exact simplification: max_i(max_{j!=i} e_j) == max_j e_j for P>=2, e>=0.
// Block = 64 threads (1 wave): 2 points in flight (lane>>5), channel = lane&31.
// ---------------------------------------------------------------------------
template <int IN>
__global__ void local_graph_kernel(const float* __restrict__ x,
                                   long groupStride, int P,
                                   const float* __restrict__ W1, const float* __restrict__ b1,
                                   const float* __restrict__ g1, const float* __restrict__ be1,
                                   const float* __restrict__ W2, const float* __restrict__ b2,
                                   const float* __restrict__ g2, const float* __restrict__ be2,
                                   float* __restrict__ out)
{
    const int g    = blockIdx.x;
    const int lane = threadIdx.x;     // 0..63
    const int sub  = lane >> 5;       // 0 or 1 (which point of the pair)
    const int c    = lane & 31;       // channel

    const float* xg = x + (long)g * groupStride;

    // Preload weight columns (shared across all points of the group)
    float w1c[IN];
#pragma unroll
    for (int k = 0; k < IN; ++k) w1c[k] = W1[k * HH + c];
    float w2c[HH];
#pragma unroll
    for (int k = 0; k < HH; ++k) w2c[k] = W2[k * HH + c];
    const float b1c = b1[c], g1c = g1[c], be1c = be1[c];
    const float b2c = b2[c], g2c = g2[c], be2c = be2[c];

    float cmax = -1e30f;

    for (int p0 = 0; p0 < P; p0 += 2) {
        const int p = p0 + sub;                 // P is even (20 or 32)
        const float* xp = xg + (long)p * IN;

        // MLP layer 1
        float h = b1c;
#pragma unroll
        for (int k = 0; k < IN; ++k) h = fmaf(xp[k], w1c[k], h);

        // LayerNorm over 32 channels (within 32-lane segment)
        float s = h;
#pragma unroll
        for (int off = 16; off >= 1; off >>= 1) s += __shfl_xor(s, off, 32);
        const float mu = s * (1.0f / 32.0f);
        float d = h - mu;
        float sq = d * d;
#pragma unroll
        for (int off = 16; off >= 1; off >>= 1) sq += __shfl_xor(sq, off, 32);
        const float var = sq * (1.0f / 32.0f);
        float a = d * rsqrtf(var + 1e-5f) * g1c + be1c;
        a = fmaxf(a, 0.0f);                     // ReLU

        // MLP layer 2: needs all 32 activations of this point's segment
        float h2 = b2c;
#pragma unroll
        for (int k = 0; k < HH; ++k) h2 = fmaf(__shfl(a, k, 32), w2c[k], h2);

        float s2 = h2;
#pragma unroll
        for (int off = 16; off >= 1; off >>= 1) s2 += __shfl_xor(s2, off, 32);
        const float mu2 = s2 * (1.0f / 32.0f);
        float d2 = h2 - mu2;
        float sq2 = d2 * d2;
#pragma unroll
        for (int off = 16; off >= 1; off >>= 1) sq2 += __shfl_xor(sq2, off, 32);
        const float var2 = sq2 * (1.0f / 32.0f);
        float e = d2 * rsqrtf(var2 + 1e-5f) * g2c + be2c;
        e = fmaxf(e, 0.0f);

        cmax = fmaxf(cmax, e);
    }

    // combine the two point-subgroups (lane c with lane c+32)
    const float other = __shfl_xor(cmax, 32);
    cmax = fmaxf(cmax, other);
    if (sub == 0) {
        out[(long)g * EE + c]      = cmax;   // e-half
        out[(long)g * EE + 32 + c] = cmax;   // nb-half == e-half (exact)
    }
}

// ---------------------------------------------------------------------------
// QKV for a2m: one block per (b, kv-row r in 0..128). Row 0 = target,
// rows 1..128 = map_emb rows 0..127 (same data used for the Q of row r-1).
// Q is pre-scaled by 1/8.
// ---------------------------------------------------------------------------
__global__ void qkv_a2m_kernel(const float* __restrict__ map_emb,   // [B,128,64]
                               const float* __restrict__ target,    // [B,64]
                               const float* __restrict__ Wq, const float* __restrict__ bq,
                               const float* __restrict__ Wk, const float* __restrict__ bk,
                               const float* __restrict__ Wv, const float* __restrict__ bv,
                               float* __restrict__ Qb,  // [B,128,64]
                               float* __restrict__ Kb,  // [B,129,64]
                               float* __restrict__ Vb)  // [B,129,64]
{
    const int blk = blockIdx.x;
    const int b = blk / 129;
    const int r = blk % 129;
    const int c = threadIdx.x;  // 0..63

    __shared__ float row[EE];
    const float* src = (r == 0) ? (target + (long)b * EE)
                                : (map_emb + ((long)b * MM + (r - 1)) * EE);
    row[c] = src[c];
    __syncthreads();

    float k_ = bk[c], v_ = bv[c];
#pragma unroll 8
    for (int i = 0; i < EE; ++i) {
        const float xv = row[i];
        k_ = fmaf(xv, Wk[i * EE + c], k_);
        v_ = fmaf(xv, Wv[i * EE + c], v_);
    }
    Kb[((long)b * 129 + r) * EE + c] = k_;
    Vb[((long)b * 129 + r) * EE + c] = v_;

    if (r > 0) {
        float q_ = bq[c];
#pragma unroll 8
        for (int i = 0; i < EE; ++i) q_ = fmaf(row[i], Wq[i * EE + c], q_);
        Qb[((long)b * MM + (r - 1)) * EE + c] = q_ * 0.125f;
    }
}

// ---------------------------------------------------------------------------
// a2m attention + output proj + residual. One block (1 wave) per (b, query).
// Writes map_emb2 directly into d_out rows 1..128.
// ---------------------------------------------------------------------------
__global__ void attn_a2m_kernel(const float* __restrict__ Qb,
                                const float* __restrict__ Kb,
                                const float* __restrict__ Vb,
                                const float* __restrict__ Wo, const float* __restrict__ bo,
                                const float* __restrict__ map_emb,
                                float* __restrict__ out)   // [B,129,64]
{
    const int blk  = blockIdx.x;
    const int b    = blk >> 7;
    const int q    = blk & 127;
    const int lane = threadIdx.x;

    __shared__ float qrow[EE];
    __shared__ float sc[129];
    __shared__ float av[EE];

    qrow[lane] = Qb[((long)b * MM + q) * EE + lane];
    __syncthreads();

    const float* Kbase = Kb + (long)b * 129 * EE;
    float mx = -1e30f;
    for (int j = lane; j < 129; j += 64) {
        const float* kr = Kbase + (long)j * EE;
        float s = 0.0f;
#pragma unroll 8
        for (int i = 0; i < EE; ++i) s = fmaf(qrow[i], kr[i], s);
        sc[j] = s;
        mx = fmaxf(mx, s);
    }
#pragma unroll
    for (int off = 32; off >= 1; off >>= 1) mx = fmaxf(mx, __shfl_xor(mx, off));

    float sum = 0.0f;
    for (int j = lane; j < 129; j += 64) {
        const float e = __expf(sc[j] - mx);
        sc[j] = e;
        sum += e;
    }
#pragma unroll
    for (int off = 32; off >= 1; off >>= 1) sum += __shfl_xor(sum, off);
    const float inv = 1.0f / sum;
    __syncthreads();   // make exp'd scores visible to all lanes

    const float* Vbase = Vb + (long)b * 129 * EE;
    float acc = 0.0f;
    for (int j = 0; j < 129; ++j) acc = fmaf(sc[j], Vbase[(long)j * EE + lane], acc);
    acc *= inv;
    av[lane] = acc;
    __syncthreads();

    float o = bo[lane];
#pragma unroll 8
    for (int i = 0; i < EE; ++i) o = fmaf(av[i], Wo[i * EE + lane], o);

    const float res = map_emb[((long)b * MM + q) * EE + lane] + o;
    out[((long)b * 129 + 1 + q) * EE + lane] = res;
}

// ---------------------------------------------------------------------------
// K2/V2 for t_m2a, reading map_emb2 from d_out rows 1..128.
// ---------------------------------------------------------------------------
__global__ void kv2_kernel(const float* __restrict__ out,
                           const float* __restrict__ Wk, const float* __restrict__ bk,
                           const float* __restrict__ Wv, const float* __restrict__ bv,
                           float* __restrict__ K2,   // [B,128,64]
                           float* __restrict__ V2)   // [B,128,64]
{
    const int blk = blockIdx.x;
    const int b = blk >> 7;
    const int r = blk & 127;
    const int c = threadIdx.x;

    __shared__ float row[EE];
    row[c] = out[((long)b * 129 + 1 + r) * EE + c];
    __syncthreads();

    float k_ = bk[c], v_ = bv[c];
#pragma unroll 8
    for (int i = 0; i < EE; ++i) {
        const float xv = row[i];
        k_ = fmaf(xv, Wk[i * EE + c], k_);
        v_ = fmaf(xv, Wv[i * EE + c], v_);
    }
    K2[((long)b * MM + r) * EE + c] = k_;
    V2[((long)b * MM + r) * EE + c] = v_;
}

// ---------------------------------------------------------------------------
// Target row: t_a (exact single-token shortcut) + t_m2a attention over 128
// map tokens. One block (1 wave) per batch. Writes d_out row 0.
// ---------------------------------------------------------------------------
__global__ void target_kernel(const float* __restrict__ target,
                              const float* __restrict__ K2, const float* __restrict__ V2,
                              const float* __restrict__ Wq2, const float* __restrict__ bq2,
                              const float* __restrict__ Wo2, const float* __restrict__ bo2,
                              const float* __restrict__ Wv1, const float* __restrict__ bv1,
                              const float* __restrict__ Wo1, const float* __restrict__ bo1,
                              float* __restrict__ out)
{
    const int b    = blockIdx.x;
    const int lane = threadIdx.x;

    __shared__ float t[EE];
    __shared__ float tmp[EE];
    __shared__ float sc[128];
    __shared__ float av[EE];

    t[lane] = target[(long)b * EE + lane];
    __syncthreads();

    // t_a = (t @ Wv1 + bv1) @ Wo1 + bo1   (softmax over one key == 1)
    float v1 = bv1[lane];
#pragma unroll 8
    for (int i = 0; i < EE; ++i) v1 = fmaf(t[i], Wv1[i * EE + lane], v1);
    tmp[lane] = v1;
    __syncthreads();
    float ta = bo1[lane];
#pragma unroll 8
    for (int i = 0; i < EE; ++i) ta = fmaf(tmp[i], Wo1[i * EE + lane], ta);
    __syncthreads();

    // t_m2a: q_t (pre-scaled)
    float qt = bq2[lane];
#pragma unroll 8
    for (int i = 0; i < EE; ++i) qt = fmaf(t[i], Wq2[i * EE + lane], qt);
    tmp[lane] = qt * 0.125f;
    __syncthreads();

    const float* Kb = K2 + (long)b * MM * EE;
    float mx = -1e30f;
    for (int j = lane; j < MM; j += 64) {
        const float* kr = Kb + (long)j * EE;
        float s = 0.0f;
#pragma unroll 8
        for (int i = 0; i < EE; ++i) s = fmaf(tmp[i], kr[i], s);
        sc[j] = s;
        mx = fmaxf(mx, s);
    }
#pragma unroll
    for (int off = 32; off >= 1; off >>= 1) mx = fmaxf(mx, __shfl_xor(mx, off));
    float sum = 0.0f;
    for (int j = lane; j < MM; j += 64) {
        const float e = __expf(sc[j] - mx);
        sc[j] = e;
        sum += e;
    }
#pragma unroll
    for (int off = 32; off >= 1; off >>= 1) sum += __shfl_xor(sum, off);
    const float inv = 1.0f / sum;
    __syncthreads();

    const float* Vb = V2 + (long)b * MM * EE;
    float acc = 0.0f;
    for (int j = 0; j < MM; ++j) acc = fmaf(sc[j], Vb[(long)j * EE + lane], acc);
    acc *= inv;
    av[lane] = acc;
    __syncthreads();

    float o = bo2[lane];
#pragma unroll 8
    for (int i = 0; i < EE; ++i) o = fmaf(av[i], Wo2[i * EE + lane], o);

    out[(long)b * 129 * EE + lane] = ta + o;
}

// ---------------------------------------------------------------------------
extern "C" void kernel_launch(void* const* d_in, const int* in_sizes, int n_in,
                              void* d_out, int out_size, void* d_ws, size_t ws_size,
                              hipStream_t stream)
{
    const float* map_states   = (const float*)d_in[0];
    const float* agent_states = (const float*)d_in[1];
    const float* m_W1 = (const float*)d_in[2];
    const float* m_b1 = (const float*)d_in[3];
    const float* m_g1 = (const float*)d_in[4];
    const float* m_be1 = (const float*)d_in[5];
    const float* m_W2 = (const float*)d_in[6];
    const float* m_b2 = (const float*)d_in[7];
    const float* m_g2 = (const float*)d_in[8];
    const float* m_be2 = (const float*)d_in[9];
    const float* a_W1 = (const float*)d_in[10];
    const float* a_b1 = (const float*)d_in[11];
    const float* a_g1 = (const float*)d_in[12];
    const float* a_be1 = (const float*)d_in[13];
    const float* a_W2 = (const float*)d_in[14];
    const float* a_b2 = (const float*)d_in[15];
    const float* a_g2 = (const float*)d_in[16];
    const float* a_be2 = (const float*)d_in[17];
    const float* att_Wq = (const float*)d_in[18];
    const float* att_bq = (const float*)d_in[19];
    const float* att_Wk = (const float*)d_in[20];
    const float* att_bk = (const float*)d_in[21];
    const float* att_Wv = (const float*)d_in[22];
    const float* att_bv = (const float*)d_in[23];
    const float* att_Wo = (const float*)d_in[24];
    const float* att_bo = (const float*)d_in[25];

    float* out = (float*)d_out;

    // ws layout (floats)
    float* ws       = (float*)d_ws;
    float* map_emb  = ws;                         // 32*128*64 = 262144
    float* target   = map_emb + BB * MM * EE;     // 32*64    = 2048
    float* Qb       = target + BB * EE;           // 262144
    float* Kb       = Qb + BB * MM * EE;          // 32*129*64 = 264192
    float* Vb       = Kb + BB * 129 * EE;         // 264192
    float* K2       = Qb;                         // reuse Qb after attn (stream-ordered)
    float* V2       = Kb;                         // reuse Kb after attn

    // weight head offsets: att_W* is (3,64,64), att_b* is (3,64)
    const float* Wq0 = att_Wq + 0 * EE * EE; const float* bq0 = att_bq + 0 * EE;
    const float* Wk0 = att_Wk + 0 * EE * EE; const float* bk0 = att_bk + 0 * EE;
    const float* Wv0 = att_Wv + 0 * EE * EE; const float* bv0 = att_bv + 0 * EE;
    const float* Wo0 = att_Wo + 0 * EE * EE; const float* bo0 = att_bo + 0 * EE;
    const float* Wv1 = att_Wv + 1 * EE * EE; const float* bv1 = att_bv + 1 * EE;
    const float* Wo1 = att_Wo + 1 * EE * EE; const float* bo1 = att_bo + 1 * EE;
    const float* Wq2 = att_Wq + 2 * EE * EE; const float* bq2 = att_bq + 2 * EE;
    const float* Wk2 = att_Wk + 2 * EE * EE; const float* bk2 = att_bk + 2 * EE;
    const float* Wv2 = att_Wv + 2 * EE * EE; const float* bv2 = att_bv + 2 * EE;
    const float* Wo2 = att_Wo + 2 * EE * EE; const float* bo2 = att_bo + 2 * EE;

    // 1. map local graph: groups = B*M
    hipLaunchKernelGGL((local_graph_kernel<16>), dim3(BB * MM), dim3(64), 0, stream,
                       map_states, (long)(PP * 16), PP,
                       m_W1, m_b1, m_g1, m_be1, m_W2, m_b2, m_g2, m_be2, map_emb);

    // 2. agent local graph (only agent 0 of each batch is used): groups = B
    hipLaunchKernelGGL((local_graph_kernel<4>), dim3(BB), dim3(64), 0, stream,
                       agent_states, (long)(AA * TT * 4), TT,
                       a_W1, a_b1, a_g1, a_be1, a_W2, a_b2, a_g2, a_be2, target);

    // 3. Q/K/V for a2m
    hipLaunchKernelGGL(qkv_a2m_kernel, dim3(BB * 129), dim3(64), 0, stream,
                       map_emb, target, Wq0, bq0, Wk0, bk0, Wv0, bv0, Qb, Kb, Vb);

    // 4. a2m attention + residual -> d_out rows 1..128
    hipLaunchKernelGGL(attn_a2m_kernel, dim3(BB * MM), dim3(64), 0, stream,
                       Qb, Kb, Vb, Wo0, bo0, map_emb, out);

    // 5. K2/V2 for t_m2a from map_emb2 (d_out rows 1..128)
    hipLaunchKernelGGL(kv2_kernel, dim3(BB * MM), dim3(64), 0, stream,
                       out, Wk2, bk2, Wv2, bv2, K2, V2);

    // 6. target row -> d_out row 0
    hipLaunchKernelGGL(target_kernel, dim3(BB), dim3(64), 0, stream,
                       target, K2, V2, Wq2, bq2, Wo2, bo2, Wv1, bv1, Wo1, bo1, out);
}

// Round 2
// 196.032 us; speedup vs baseline: 1.1266x; 1.1266x over previous
//
#include <hip/hip_runtime.h>

// Sizes (fixed by the problem)
#define BB 32
#define MM 128
#define PP 20
#define AA 32
#define TT 32
#define HH 32
#define EE 64

// ---------------------------------------------------------------------------
// Vectorized 64x64 matvec: out[c] = sum_i x[i] * W[i][c].
// Lane decomposition: s = lane>>4 (i-range), t = lane&15 (4 channels 4t..4t+3).
// Returns fully-reduced float4 (valid in ALL lanes). W row-major [64][64].
// ---------------------------------------------------------------------------
__device__ __forceinline__ float4 matvec64(const float* __restrict__ W,
                                           const float* __restrict__ xrow,
                                           int s, int t)
{
    const float4* __restrict__ Wv = (const float4*)W;
    const float4* __restrict__ xv = (const float4*)xrow;
    float4 acc = make_float4(0.f, 0.f, 0.f, 0.f);
#pragma unroll
    for (int ii = 0; ii < 4; ++ii) {
        const float4 xx = xv[s * 4 + ii];
        const int ib = s * 16 + ii * 4;
        const float4 w0 = Wv[(ib + 0) * 16 + t];
        const float4 w1 = Wv[(ib + 1) * 16 + t];
        const float4 w2 = Wv[(ib + 2) * 16 + t];
        const float4 w3 = Wv[(ib + 3) * 16 + t];
        acc.x = fmaf(xx.x, w0.x, acc.x); acc.y = fmaf(xx.x, w0.y, acc.y);
        acc.z = fmaf(xx.x, w0.z, acc.z); acc.w = fmaf(xx.x, w0.w, acc.w);
        acc.x = fmaf(xx.y, w1.x, acc.x); acc.y = fmaf(xx.y, w1.y, acc.y);
        acc.z = fmaf(xx.y, w1.z, acc.z); acc.w = fmaf(xx.y, w1.w, acc.w);
        acc.x = fmaf(xx.z, w2.x, acc.x); acc.y = fmaf(xx.z, w2.y, acc.y);
        acc.z = fmaf(xx.z, w2.z, acc.z); acc.w = fmaf(xx.z, w2.w, acc.w);
        acc.x = fmaf(xx.w, w3.x, acc.x); acc.y = fmaf(xx.w, w3.y, acc.y);
        acc.z = fmaf(xx.w, w3.z, acc.z); acc.w = fmaf(xx.w, w3.w, acc.w);
    }
    // reduce across s (lanes differ in bits 4,5)
    acc.x += __shfl_xor(acc.x, 16); acc.y += __shfl_xor(acc.y, 16);
    acc.z += __shfl_xor(acc.z, 16); acc.w += __shfl_xor(acc.w, 16);
    acc.x += __shfl_xor(acc.x, 32); acc.y += __shfl_xor(acc.y, 32);
    acc.z += __shfl_xor(acc.z, 32); acc.w += __shfl_xor(acc.w, 32);
    return acc;
}

// ---------------------------------------------------------------------------
// Local graph body: per group, 2-layer MLP+LN+ReLU over P points of IN dims,
// then per-channel max; duplicated into 64 channels (exact: the neighbor-max
// half equals the plain max half for P>=2, e>=0).
// ---------------------------------------------------------------------------
template <int IN>
__device__ __forceinline__ void lg_body(const float* __restrict__ xg, int P,
                                        const float* __restrict__ W1, const float* __restrict__ b1,
                                        const float* __restrict__ g1, const float* __restrict__ be1,
                                        const float* __restrict__ W2, const float* __restrict__ b2,
                                        const float* __restrict__ g2, const float* __restrict__ be2,
                                        float* __restrict__ outRow)
{
    const int lane = threadIdx.x;
    const int sub  = lane >> 5;
    const int c    = lane & 31;

    float w1c[IN];
#pragma unroll
    for (int k = 0; k < IN; ++k) w1c[k] = W1[k * HH + c];
    float w2c[HH];
#pragma unroll
    for (int k = 0; k < HH; ++k) w2c[k] = W2[k * HH + c];
    const float b1c = b1[c], g1c = g1[c], be1c = be1[c];
    const float b2c = b2[c], g2c = g2[c], be2c = be2[c];

    float cmax = -1e30f;

    for (int p0 = 0; p0 < P; p0 += 2) {
        const int p = p0 + sub;                 // P even
        const float* xp = xg + (long)p * IN;

        float h = b1c;
#pragma unroll
        for (int k = 0; k < IN; ++k) h = fmaf(xp[k], w1c[k], h);

        float sdot = h;
#pragma unroll
        for (int off = 16; off >= 1; off >>= 1) sdot += __shfl_xor(sdot, off, 32);
        const float mu = sdot * (1.0f / 32.0f);
        float d = h - mu;
        float sq = d * d;
#pragma unroll
        for (int off = 16; off >= 1; off >>= 1) sq += __shfl_xor(sq, off, 32);
        const float var = sq * (1.0f / 32.0f);
        float a = d * rsqrtf(var + 1e-5f) * g1c + be1c;
        a = fmaxf(a, 0.0f);

        float h2 = b2c;
#pragma unroll
        for (int k = 0; k < HH; ++k) h2 = fmaf(__shfl(a, k, 32), w2c[k], h2);

        float s2 = h2;
#pragma unroll
        for (int off = 16; off >= 1; off >>= 1) s2 += __shfl_xor(s2, off, 32);
        const float mu2 = s2 * (1.0f / 32.0f);
        float d2 = h2 - mu2;
        float sq2 = d2 * d2;
#pragma unroll
        for (int off = 16; off >= 1; off >>= 1) sq2 += __shfl_xor(sq2, off, 32);
        const float var2 = sq2 * (1.0f / 32.0f);
        float e = d2 * rsqrtf(var2 + 1e-5f) * g2c + be2c;
        e = fmaxf(e, 0.0f);

        cmax = fmaxf(cmax, e);
    }

    const float other = __shfl_xor(cmax, 32);
    cmax = fmaxf(cmax, other);
    if (sub == 0) {
        outRow[c]      = cmax;
        outRow[32 + c] = cmax;
    }
}

// Fused: blocks [0, B*M) do map groups; blocks [B*M, B*M+B) do agent 0 of each batch.
__global__ void lg_fused_kernel(const float* __restrict__ map_states,
                                const float* __restrict__ agent_states,
                                const float* __restrict__ mW1, const float* __restrict__ mb1,
                                const float* __restrict__ mg1, const float* __restrict__ mbe1,
                                const float* __restrict__ mW2, const float* __restrict__ mb2,
                                const float* __restrict__ mg2, const float* __restrict__ mbe2,
                                const float* __restrict__ aW1, const float* __restrict__ ab1,
                                const float* __restrict__ ag1, const float* __restrict__ abe1,
                                const float* __restrict__ aW2, const float* __restrict__ ab2,
                                const float* __restrict__ ag2, const float* __restrict__ abe2,
                                float* __restrict__ map_emb, float* __restrict__ target)
{
    const int g = blockIdx.x;
    if (g < BB * MM) {
        lg_body<16>(map_states + (long)g * PP * 16, PP,
                    mW1, mb1, mg1, mbe1, mW2, mb2, mg2, mbe2,
                    map_emb + (long)g * EE);
    } else {
        const int b = g - BB * MM;
        lg_body<4>(agent_states + (long)b * AA * TT * 4, TT,
                   aW1, ab1, ag1, abe1, aW2, ab2, ag2, abe2,
                   target + (long)b * EE);
    }
}

// ---------------------------------------------------------------------------
// K/V for a2m: one block per (b, kv-row r in 0..128). Row 0 = target,
// rows 1..128 = map_emb rows 0..127.
// ---------------------------------------------------------------------------
__global__ void kv_a2m_kernel(const float* __restrict__ map_emb,
                              const float* __restrict__ target,
                              const float* __restrict__ Wk, const float* __restrict__ bk,
                              const float* __restrict__ Wv, const float* __restrict__ bv,
                              float* __restrict__ Kb,  // [B,129,64]
                              float* __restrict__ Vb)  // [B,129,64]
{
    const int blk = blockIdx.x;
    const int b = blk / 129;
    const int r = blk % 129;
    const int lane = threadIdx.x;
    const int s = lane >> 4, t = lane & 15;

    __shared__ __align__(16) float xrow[EE];
    const float* src = (r == 0) ? (target + (long)b * EE)
                                : (map_emb + ((long)b * MM + (r - 1)) * EE);
    xrow[lane] = src[lane];
    __syncthreads();

    const float4 k4 = matvec64(Wk, xrow, s, t);
    const float4 v4 = matvec64(Wv, xrow, s, t);
    if (s == 0) {
        const float4 kb4 = ((const float4*)bk)[t];
        const float4 vb4 = ((const float4*)bv)[t];
        float4 ko, vo;
        ko.x = k4.x + kb4.x; ko.y = k4.y + kb4.y; ko.z = k4.z + kb4.z; ko.w = k4.w + kb4.w;
        vo.x = v4.x + vb4.x; vo.y = v4.y + vb4.y; vo.z = v4.z + vb4.z; vo.w = v4.w + vb4.w;
        ((float4*)(Kb + ((long)b * 129 + r) * EE))[t] = ko;
        ((float4*)(Vb + ((long)b * 129 + r) * EE))[t] = vo;
    }
}

// ---------------------------------------------------------------------------
// a2m attention, fused: computes Q in-block, scores (coalesced float4 K reads),
// softmax, PV, output proj + residual -> d_out rows 1..128, and the K2/V2
// projection of the result row (for the later t_m2a attention).
// One block (1 wave) per (b, query).
// ---------------------------------------------------------------------------
__global__ void attn_fused_kernel(const float* __restrict__ map_emb,
                                  const float* __restrict__ Kb,
                                  const float* __restrict__ Vb,
                                  const float* __restrict__ Wq, const float* __restrict__ bq,
                                  const float* __restrict__ Wo, const float* __restrict__ bo,
                                  const float* __restrict__ Wk2, const float* __restrict__ bk2,
                                  const float* __restrict__ Wv2, const float* __restrict__ bv2,
                                  float* __restrict__ K2,   // [B,128,64]
                                  float* __restrict__ V2,   // [B,128,64]
                                  float* __restrict__ out)  // [B,129,64]
{
    const int blk  = blockIdx.x;
    const int b    = blk >> 7;
    const int q    = blk & 127;
    const int lane = threadIdx.x;
    const int s = lane >> 4, t = lane & 15;

    __shared__ __align__(16) float xrow[EE];
    __shared__ __align__(16) float sc[132];
    __shared__ __align__(16) float av[EE];
    __shared__ __align__(16) float resrow[EE];

    xrow[lane] = map_emb[((long)b * MM + q) * EE + lane];
    __syncthreads();

    // Q projection (pre-scaled). q4 = channels 4t..4t+3 — exactly what the
    // t-group score reduction needs.
    float4 q4 = matvec64(Wq, xrow, s, t);
    {
        const float4 bq4 = ((const float4*)bq)[t];
        q4.x = (q4.x + bq4.x) * 0.125f;
        q4.y = (q4.y + bq4.y) * 0.125f;
        q4.z = (q4.z + bq4.z) * 0.125f;
        q4.w = (q4.w + bq4.w) * 0.125f;
    }

    // Scores: 4 keys per iteration (j = 4*it + s), coalesced float4 K reads.
    const float* Kbase = Kb + (long)b * 129 * EE;
    float mx = -1e30f;
#pragma unroll 4
    for (int it = 0; it < 33; ++it) {
        const int j = it * 4 + s;
        const bool valid = (j < 129);
        float p = 0.0f;
        if (valid) {
            const float4 k4 = ((const float4*)(Kbase + (long)j * EE))[t];
            p = q4.x * k4.x + q4.y * k4.y + q4.z * k4.z + q4.w * k4.w;
        }
        p += __shfl_xor(p, 1); p += __shfl_xor(p, 2);
        p += __shfl_xor(p, 4); p += __shfl_xor(p, 8);
        if (valid) {
            mx = fmaxf(mx, p);
            if (t == 0) sc[j] = p;
        }
    }
#pragma unroll
    for (int off = 32; off >= 1; off >>= 1) mx = fmaxf(mx, __shfl_xor(mx, off));
    __syncthreads();

    float sum = 0.0f;
    for (int j = lane; j < 129; j += 64) {
        const float e = __expf(sc[j] - mx);
        sc[j] = e;
        sum += e;
    }
#pragma unroll
    for (int off = 32; off >= 1; off >>= 1) sum += __shfl_xor(sum, off);
    const float inv = 1.0f / sum;
    __syncthreads();

    // PV: coalesced V reads, float4 score broadcasts.
    const float* Vbase = Vb + (long)b * 129 * EE;
    float acc = 0.0f;
#pragma unroll 4
    for (int j0 = 0; j0 < 128; j0 += 4) {
        const float4 s4 = *(const float4*)&sc[j0];
        acc = fmaf(s4.x, Vbase[(long)(j0 + 0) * EE + lane], acc);
        acc = fmaf(s4.y, Vbase[(long)(j0 + 1) * EE + lane], acc);
        acc = fmaf(s4.z, Vbase[(long)(j0 + 2) * EE + lane], acc);
        acc = fmaf(s4.w, Vbase[(long)(j0 + 3) * EE + lane], acc);
    }
    acc = fmaf(sc[128], Vbase[(long)128 * EE + lane], acc);
    acc *= inv;
    av[lane] = acc;
    __syncthreads();

    // Output projection + residual
    const float4 o4 = matvec64(Wo, av, s, t);
    const float4 bo4 = ((const float4*)bo)[t];
    const float4 x4 = ((const float4*)xrow)[t];
    float4 res;
    res.x = o4.x + bo4.x + x4.x;
    res.y = o4.y + bo4.y + x4.y;
    res.z = o4.z + bo4.z + x4.z;
    res.w = o4.w + bo4.w + x4.w;
    if (s == 0) {
        ((float4*)(out + ((long)b * 129 + 1 + q) * EE))[t] = res;
        ((float4*)resrow)[t] = res;
    }
    __syncthreads();

    // Fused K2/V2 projection of the result row
    const float4 k4 = matvec64(Wk2, resrow, s, t);
    const float4 v4 = matvec64(Wv2, resrow, s, t);
    if (s == 0) {
        const float4 kb4 = ((const float4*)bk2)[t];
        const float4 vb4 = ((const float4*)bv2)[t];
        float4 ko, vo;
        ko.x = k4.x + kb4.x; ko.y = k4.y + kb4.y; ko.z = k4.z + kb4.z; ko.w = k4.w + kb4.w;
        vo.x = v4.x + vb4.x; vo.y = v4.y + vb4.y; vo.z = v4.z + vb4.z; vo.w = v4.w + vb4.w;
        ((float4*)(K2 + ((long)b * MM + q) * EE))[t] = ko;
        ((float4*)(V2 + ((long)b * MM + q) * EE))[t] = vo;
    }
}

// ---------------------------------------------------------------------------
// Target row: t_a (exact single-token shortcut) + t_m2a attention over 128
// map tokens. One block (1 wave) per batch. Writes d_out row 0.
// ---------------------------------------------------------------------------
__global__ void target_kernel(const float* __restrict__ target,
                              const float* __restrict__ K2, const float* __restrict__ V2,
                              const float* __restrict__ Wq2, const float* __restrict__ bq2,
                              const float* __restrict__ Wo2, const float* __restrict__ bo2,
                              const float* __restrict__ Wv1, const float* __restrict__ bv1,
                              const float* __restrict__ Wo1, const float* __restrict__ bo1,
                              float* __restrict__ out)
{
    const int b    = blockIdx.x;
    const int lane = threadIdx.x;
    const int s = lane >> 4, t = lane & 15;

    __shared__ __align__(16) float trow[EE];
    __shared__ __align__(16) float tmp[EE];
    __shared__ __align__(16) float sc[128];
    __shared__ __align__(16) float av[EE];

    trow[lane] = target[(long)b * EE + lane];
    __syncthreads();

    // t_a = (t @ Wv1 + bv1) @ Wo1 + bo1
    const float4 v1 = matvec64(Wv1, trow, s, t);
    if (s == 0) {
        const float4 bv4 = ((const float4*)bv1)[t];
        float4 w; w.x = v1.x + bv4.x; w.y = v1.y + bv4.y; w.z = v1.z + bv4.z; w.w = v1.w + bv4.w;
        ((float4*)tmp)[t] = w;
    }
    __syncthreads();
    float4 ta = matvec64(Wo1, tmp, s, t);
    {
        const float4 bo4 = ((const float4*)bo1)[t];
        ta.x += bo4.x; ta.y += bo4.y; ta.z += bo4.z; ta.w += bo4.w;
    }

    // t_m2a query (pre-scaled)
    float4 q4 = matvec64(Wq2, trow, s, t);
    {
        const float4 bq4 = ((const float4*)bq2)[t];
        q4.x = (q4.x + bq4.x) * 0.125f;
        q4.y = (q4.y + bq4.y) * 0.125f;
        q4.z = (q4.z + bq4.z) * 0.125f;
        q4.w = (q4.w + bq4.w) * 0.125f;
    }

    const float* Kbase = K2 + (long)b * MM * EE;
    float mx = -1e30f;
#pragma unroll 4
    for (int it = 0; it < 32; ++it) {
        const int j = it * 4 + s;
        const float4 k4 = ((const float4*)(Kbase + (long)j * EE))[t];
        float p = q4.x * k4.x + q4.y * k4.y + q4.z * k4.z + q4.w * k4.w;
        p += __shfl_xor(p, 1); p += __shfl_xor(p, 2);
        p += __shfl_xor(p, 4); p += __shfl_xor(p, 8);
        mx = fmaxf(mx, p);
        if (t == 0) sc[j] = p;
    }
#pragma unroll
    for (int off = 32; off >= 1; off >>= 1) mx = fmaxf(mx, __shfl_xor(mx, off));
    __syncthreads();

    float sum = 0.0f;
#pragma unroll
    for (int j = lane; j < MM; j += 64) {
        const float e = __expf(sc[j] - mx);
        sc[j] = e;
        sum += e;
    }
#pragma unroll
    for (int off = 32; off >= 1; off >>= 1) sum += __shfl_xor(sum, off);
    const float inv = 1.0f / sum;
    __syncthreads();

    const float* Vbase = V2 + (long)b * MM * EE;
    float acc = 0.0f;
#pragma unroll 4
    for (int j0 = 0; j0 < 128; j0 += 4) {
        const float4 s4 = *(const float4*)&sc[j0];
        acc = fmaf(s4.x, Vbase[(long)(j0 + 0) * EE + lane], acc);
        acc = fmaf(s4.y, Vbase[(long)(j0 + 1) * EE + lane], acc);
        acc = fmaf(s4.z, Vbase[(long)(j0 + 2) * EE + lane], acc);
        acc = fmaf(s4.w, Vbase[(long)(j0 + 3) * EE + lane], acc);
    }
    acc *= inv;
    av[lane] = acc;
    __syncthreads();

    const float4 o4 = matvec64(Wo2, av, s, t);
    if (s == 0) {
        const float4 bo4 = ((const float4*)bo2)[t];
        float4 r;
        r.x = ta.x + o4.x + bo4.x;
        r.y = ta.y + o4.y + bo4.y;
        r.z = ta.z + o4.z + bo4.z;
        r.w = ta.w + o4.w + bo4.w;
        ((float4*)(out + (long)b * 129 * EE))[t] = r;
    }
}

// ---------------------------------------------------------------------------
extern "C" void kernel_launch(void* const* d_in, const int* in_sizes, int n_in,
                              void* d_out, int out_size, void* d_ws, size_t ws_size,
                              hipStream_t stream)
{
    const float* map_states   = (const float*)d_in[0];
    const float* agent_states = (const float*)d_in[1];
    const float* m_W1 = (const float*)d_in[2];
    const float* m_b1 = (const float*)d_in[3];
    const float* m_g1 = (const float*)d_in[4];
    const float* m_be1 = (const float*)d_in[5];
    const float* m_W2 = (const float*)d_in[6];
    const float* m_b2 = (const float*)d_in[7];
    const float* m_g2 = (const float*)d_in[8];
    const float* m_be2 = (const float*)d_in[9];
    const float* a_W1 = (const float*)d_in[10];
    const float* a_b1 = (const float*)d_in[11];
    const float* a_g1 = (const float*)d_in[12];
    const float* a_be1 = (const float*)d_in[13];
    const float* a_W2 = (const float*)d_in[14];
    const float* a_b2 = (const float*)d_in[15];
    const float* a_g2 = (const float*)d_in[16];
    const float* a_be2 = (const float*)d_in[17];
    const float* att_Wq = (const float*)d_in[18];
    const float* att_bq = (const float*)d_in[19];
    const float* att_Wk = (const float*)d_in[20];
    const float* att_bk = (const float*)d_in[21];
    const float* att_Wv = (const float*)d_in[22];
    const float* att_bv = (const float*)d_in[23];
    const float* att_Wo = (const float*)d_in[24];
    const float* att_bo = (const float*)d_in[25];

    float* out = (float*)d_out;

    // ws layout (floats)
    float* ws      = (float*)d_ws;
    float* map_emb = ws;                          // 32*128*64
    float* target  = map_emb + BB * MM * EE;      // 32*64
    float* Kb      = target + BB * EE;            // 32*129*64
    float* Vb      = Kb + BB * 129 * EE;          // 32*129*64
    float* K2      = Vb + BB * 129 * EE;          // 32*128*64
    float* V2      = K2 + BB * MM * EE;           // 32*128*64

    const float* Wq0 = att_Wq + 0 * EE * EE; const float* bq0 = att_bq + 0 * EE;
    const float* Wk0 = att_Wk + 0 * EE * EE; const float* bk0 = att_bk + 0 * EE;
    const float* Wv0 = att_Wv + 0 * EE * EE; const float* bv0 = att_bv + 0 * EE;
    const float* Wo0 = att_Wo + 0 * EE * EE; const float* bo0 = att_bo + 0 * EE;
    const float* Wv1 = att_Wv + 1 * EE * EE; const float* bv1 = att_bv + 1 * EE;
    const float* Wo1 = att_Wo + 1 * EE * EE; const float* bo1 = att_bo + 1 * EE;
    const float* Wq2 = att_Wq + 2 * EE * EE; const float* bq2 = att_bq + 2 * EE;
    const float* Wk2 = att_Wk + 2 * EE * EE; const float* bk2 = att_bk + 2 * EE;
    const float* Wv2 = att_Wv + 2 * EE * EE; const float* bv2 = att_bv + 2 * EE;
    const float* Wo2 = att_Wo + 2 * EE * EE; const float* bo2 = att_bo + 2 * EE;

    // 1. fused local graphs (map: 4096 blocks, agent: 32 blocks)
    hipLaunchKernelGGL(lg_fused_kernel, dim3(BB * MM + BB), dim3(64), 0, stream,
                       map_states, agent_states,
                       m_W1, m_b1, m_g1, m_be1, m_W2, m_b2, m_g2, m_be2,
                       a_W1, a_b1, a_g1, a_be1, a_W2, a_b2, a_g2, a_be2,
                       map_emb, target);

    // 2. K/V for a2m
    hipLaunchKernelGGL(kv_a2m_kernel, dim3(BB * 129), dim3(64), 0, stream,
                       map_emb, target, Wk0, bk0, Wv0, bv0, Kb, Vb);

    // 3. a2m attention (Q computed in-block) + residual + fused K2/V2
    hipLaunchKernelGGL(attn_fused_kernel, dim3(BB * MM), dim3(64), 0, stream,
                       map_emb, Kb, Vb, Wq0, bq0, Wo0, bo0,
                       Wk2, bk2, Wv2, bv2, K2, V2, out);

    // 4. target row
    hipLaunchKernelGGL(target_kernel, dim3(BB), dim3(64), 0, stream,
                       target, K2, V2, Wq2, bq2, Wo2, bo2, Wv1, bv1, Wo1, bo1, out);
}

// Round 3
// 184.224 us; speedup vs baseline: 1.1988x; 1.0641x over previous
//
#include <hip/hip_runtime.h>

// Sizes (fixed by the problem)
#define BB 32
#define MM 128
#define PP 20
#define AA 32
#define TT 32
#define HH 32
#define EE 64

// ---------------------------------------------------------------------------
// Vectorized 64x64 matvec: out[c] = sum_i x[i] * W[i][c].
// Lane decomposition within a 64-lane wave: s = lane>>4, t = lane&15
// (4 channels 4t..4t+3). Returns fully-reduced float4 (valid in ALL lanes).
// W row-major [64][64]. xrow may be LDS or global.
// ---------------------------------------------------------------------------
__device__ __forceinline__ float4 matvec64(const float* __restrict__ W,
                                           const float* __restrict__ xrow,
                                           int s, int t)
{
    const float4* __restrict__ Wv = (const float4*)W;
    const float4* __restrict__ xv = (const float4*)xrow;
    float4 acc = make_float4(0.f, 0.f, 0.f, 0.f);
#pragma unroll
    for (int ii = 0; ii < 4; ++ii) {
        const float4 xx = xv[s * 4 + ii];
        const int ib = s * 16 + ii * 4;
        const float4 w0 = Wv[(ib + 0) * 16 + t];
        const float4 w1 = Wv[(ib + 1) * 16 + t];
        const float4 w2 = Wv[(ib + 2) * 16 + t];
        const float4 w3 = Wv[(ib + 3) * 16 + t];
        acc.x = fmaf(xx.x, w0.x, acc.x); acc.y = fmaf(xx.x, w0.y, acc.y);
        acc.z = fmaf(xx.x, w0.z, acc.z); acc.w = fmaf(xx.x, w0.w, acc.w);
        acc.x = fmaf(xx.y, w1.x, acc.x); acc.y = fmaf(xx.y, w1.y, acc.y);
        acc.z = fmaf(xx.y, w1.z, acc.z); acc.w = fmaf(xx.y, w1.w, acc.w);
        acc.x = fmaf(xx.z, w2.x, acc.x); acc.y = fmaf(xx.z, w2.y, acc.y);
        acc.z = fmaf(xx.z, w2.z, acc.z); acc.w = fmaf(xx.z, w2.w, acc.w);
        acc.x = fmaf(xx.w, w3.x, acc.x); acc.y = fmaf(xx.w, w3.y, acc.y);
        acc.z = fmaf(xx.w, w3.z, acc.z); acc.w = fmaf(xx.w, w3.w, acc.w);
    }
    acc.x += __shfl_xor(acc.x, 16); acc.y += __shfl_xor(acc.y, 16);
    acc.z += __shfl_xor(acc.z, 16); acc.w += __shfl_xor(acc.w, 16);
    acc.x += __shfl_xor(acc.x, 32); acc.y += __shfl_xor(acc.y, 32);
    acc.z += __shfl_xor(acc.z, 32); acc.w += __shfl_xor(acc.w, 32);
    return acc;
}

// ---------------------------------------------------------------------------
// Fused local-graph + QKV projection kernel. 128 threads (2 waves).
// Blocks [0, B*M): map group (b,m) -> map_emb row, Qb[b][m], Kb[b][m+1], Vb[b][m+1]
// Blocks [B*M, B*M+B): agent 0 of batch b -> target[b], Kb[b][0], Vb[b][0]
// Local graph: 2-layer MLP+LN+ReLU over P points, per-channel max, duplicated
// into 64 channels (exact: neighbor-max half == plain max half for P>=2, e>=0).
// 4 points in flight (sub = tid>>5); layer-2 broadcast via per-sub LDS slot
// (8 independent ds_read_b128 instead of 32 serial bpermutes).
// ---------------------------------------------------------------------------
template <int IN>
__device__ __forceinline__ void lg_qkv_body(const float* __restrict__ xg, int P,
                                            const float* __restrict__ W1, const float* __restrict__ b1,
                                            const float* __restrict__ g1, const float* __restrict__ be1,
                                            const float* __restrict__ W2, const float* __restrict__ b2,
                                            const float* __restrict__ g2, const float* __restrict__ be2,
                                            float* __restrict__ embRow,   // global, 64 floats
                                            const float* __restrict__ Wq, const float* __restrict__ bq,
                                            const float* __restrict__ Wk, const float* __restrict__ bk,
                                            const float* __restrict__ Wv, const float* __restrict__ bv,
                                            float* __restrict__ Qrow,     // global or nullptr
                                            float* __restrict__ Krow,     // global
                                            float* __restrict__ Vrow)     // global
{
    const int tid  = threadIdx.x;      // 0..127
    const int wave = tid >> 6;
    const int lane = tid & 63;
    const int sub  = tid >> 5;         // 0..3
    const int c    = tid & 31;

    __shared__ __align__(16) float aslot[4][32];
    __shared__ __align__(16) float wmax[2][32];
    __shared__ __align__(16) float xrow[EE];

    // Weight columns (lane's channel c)
    float w1c[IN];
#pragma unroll
    for (int k = 0; k < IN; ++k) w1c[k] = W1[k * HH + c];
    float w2c[HH];
#pragma unroll
    for (int k = 0; k < HH; ++k) w2c[k] = W2[k * HH + c];
    const float b1c = b1[c], g1c = g1[c], be1c = be1[c];
    const float b2c = b2[c], g2c = g2[c], be2c = be2[c];

    float cmax = -1e30f;

    for (int p0 = 0; p0 < P; p0 += 4) {
        const int p = p0 + sub;                // P divisible by 4 (20, 32)
        const float* xp = xg + (long)p * IN;

        // layer 1 (float4 input loads, broadcast across sub's 32 lanes)
        float h = b1c;
        if (IN == 16) {
            const float4* xp4 = (const float4*)xp;
            const float4 x0 = xp4[0], x1 = xp4[1], x2 = xp4[2], x3 = xp4[3];
            h = fmaf(x0.x, w1c[0], h);  h = fmaf(x0.y, w1c[1], h);
            h = fmaf(x0.z, w1c[2], h);  h = fmaf(x0.w, w1c[3], h);
            h = fmaf(x1.x, w1c[4], h);  h = fmaf(x1.y, w1c[5], h);
            h = fmaf(x1.z, w1c[6], h);  h = fmaf(x1.w, w1c[7], h);
            h = fmaf(x2.x, w1c[8], h);  h = fmaf(x2.y, w1c[9], h);
            h = fmaf(x2.z, w1c[10], h); h = fmaf(x2.w, w1c[11], h);
            h = fmaf(x3.x, w1c[12], h); h = fmaf(x3.y, w1c[13], h);
            h = fmaf(x3.z, w1c[14], h); h = fmaf(x3.w, w1c[15], h);
        } else {
            const float4 x0 = *(const float4*)xp;
            h = fmaf(x0.x, w1c[0], h); h = fmaf(x0.y, w1c[1], h);
            h = fmaf(x0.z, w1c[2], h); h = fmaf(x0.w, w1c[3], h);
        }

        // LN over 32 channels (intra-sub)
        float sdot = h;
#pragma unroll
        for (int off = 16; off >= 1; off >>= 1) sdot += __shfl_xor(sdot, off, 32);
        const float mu = sdot * (1.0f / 32.0f);
        float d = h - mu;
        float sq = d * d;
#pragma unroll
        for (int off = 16; off >= 1; off >>= 1) sq += __shfl_xor(sq, off, 32);
        const float var = sq * (1.0f / 32.0f);
        float a = d * rsqrtf(var + 1e-5f) * g1c + be1c;
        a = fmaxf(a, 0.0f);

        // layer 2 via LDS broadcast (same-wave producer/consumer; compiler
        // inserts the lgkmcnt wait — no barrier needed)
        aslot[sub][c] = a;
        const float4* av4 = (const float4*)aslot[sub];
        float h2 = b2c;
#pragma unroll
        for (int j = 0; j < 8; ++j) {
            const float4 aa = av4[j];
            h2 = fmaf(aa.x, w2c[4 * j + 0], h2);
            h2 = fmaf(aa.y, w2c[4 * j + 1], h2);
            h2 = fmaf(aa.z, w2c[4 * j + 2], h2);
            h2 = fmaf(aa.w, w2c[4 * j + 3], h2);
        }

        float s2 = h2;
#pragma unroll
        for (int off = 16; off >= 1; off >>= 1) s2 += __shfl_xor(s2, off, 32);
        const float mu2 = s2 * (1.0f / 32.0f);
        float d2 = h2 - mu2;
        float sq2 = d2 * d2;
#pragma unroll
        for (int off = 16; off >= 1; off >>= 1) sq2 += __shfl_xor(sq2, off, 32);
        const float var2 = sq2 * (1.0f / 32.0f);
        float e = d2 * rsqrtf(var2 + 1e-5f) * g2c + be2c;
        e = fmaxf(e, 0.0f);

        cmax = fmaxf(cmax, e);
    }

    // combine subs: intra-wave (sub pairs differ in lane bit 5)
    cmax = fmaxf(cmax, __shfl_xor(cmax, 32));
    if (lane < 32) wmax[wave][lane] = cmax;
    __syncthreads();

    // build xrow (duplicated 64-channel row) + write global emb row
    if (tid < 32) {
        const float fin = fmaxf(wmax[0][tid], wmax[1][tid]);
        xrow[tid]      = fin;
        xrow[tid + 32] = fin;
        embRow[tid]      = fin;
        embRow[tid + 32] = fin;
    }
    __syncthreads();

    // QKV projections: wave0 -> Q (if needed) + K; wave1 -> V
    const int s = lane >> 4, t = lane & 15;
    if (wave == 0) {
        if (Qrow) {
            float4 q4 = matvec64(Wq, xrow, s, t);
            if (s == 0) {
                const float4 bq4 = ((const float4*)bq)[t];
                float4 qo;
                qo.x = (q4.x + bq4.x) * 0.125f;
                qo.y = (q4.y + bq4.y) * 0.125f;
                qo.z = (q4.z + bq4.z) * 0.125f;
                qo.w = (q4.w + bq4.w) * 0.125f;
                ((float4*)Qrow)[t] = qo;
            }
        }
        float4 k4 = matvec64(Wk, xrow, s, t);
        if (s == 0) {
            const float4 kb4 = ((const float4*)bk)[t];
            float4 ko;
            ko.x = k4.x + kb4.x; ko.y = k4.y + kb4.y;
            ko.z = k4.z + kb4.z; ko.w = k4.w + kb4.w;
            ((float4*)Krow)[t] = ko;
        }
    } else {
        float4 v4 = matvec64(Wv, xrow, s, t);
        if (s == 0) {
            const float4 vb4 = ((const float4*)bv)[t];
            float4 vo;
            vo.x = v4.x + vb4.x; vo.y = v4.y + vb4.y;
            vo.z = v4.z + vb4.z; vo.w = v4.w + vb4.w;
            ((float4*)Vrow)[t] = vo;
        }
    }
}

__global__ void lg_qkv_kernel(const float* __restrict__ map_states,
                              const float* __restrict__ agent_states,
                              const float* __restrict__ mW1, const float* __restrict__ mb1,
                              const float* __restrict__ mg1, const float* __restrict__ mbe1,
                              const float* __restrict__ mW2, const float* __restrict__ mb2,
                              const float* __restrict__ mg2, const float* __restrict__ mbe2,
                              const float* __restrict__ aW1, const float* __restrict__ ab1,
                              const float* __restrict__ ag1, const float* __restrict__ abe1,
                              const float* __restrict__ aW2, const float* __restrict__ ab2,
                              const float* __restrict__ ag2, const float* __restrict__ abe2,
                              const float* __restrict__ Wq, const float* __restrict__ bq,
                              const float* __restrict__ Wk, const float* __restrict__ bk,
                              const float* __restrict__ Wv, const float* __restrict__ bv,
                              float* __restrict__ map_emb,  // [B,128,64]
                              float* __restrict__ target,   // [B,64]
                              float* __restrict__ Qb,       // [B,128,64]
                              float* __restrict__ Kb,       // [B,129,64]
                              float* __restrict__ Vb)       // [B,129,64]
{
    const int g = blockIdx.x;
    if (g < BB * MM) {
        const int b = g >> 7, m = g & 127;
        lg_qkv_body<16>(map_states + (long)g * PP * 16, PP,
                        mW1, mb1, mg1, mbe1, mW2, mb2, mg2, mbe2,
                        map_emb + (long)g * EE,
                        Wq, bq, Wk, bk, Wv, bv,
                        Qb + (long)g * EE,
                        Kb + ((long)b * 129 + 1 + m) * EE,
                        Vb + ((long)b * 129 + 1 + m) * EE);
    } else {
        const int b = g - BB * MM;
        lg_qkv_body<4>(agent_states + (long)b * AA * TT * 4, TT,
                       aW1, ab1, ag1, abe1, aW2, ab2, ag2, abe2,
                       target + (long)b * EE,
                       Wq, bq, Wk, bk, Wv, bv,
                       nullptr,
                       Kb + (long)b * 129 * EE,
                       Vb + (long)b * 129 * EE);
    }
}

// ---------------------------------------------------------------------------
// a2m attention: loads precomputed Q, scores (coalesced float4 K), softmax,
// PV (4 accumulators), output proj + residual -> d_out rows 1..128, fused
// K2/V2 projection of the result row. One block (1 wave) per (b, query).
// ---------------------------------------------------------------------------
__global__ void attn_fused_kernel(const float* __restrict__ map_emb,
                                  const float* __restrict__ Qb,
                                  const float* __restrict__ Kb,
                                  const float* __restrict__ Vb,
                                  const float* __restrict__ Wo, const float* __restrict__ bo,
                                  const float* __restrict__ Wk2, const float* __restrict__ bk2,
                                  const float* __restrict__ Wv2, const float* __restrict__ bv2,
                                  float* __restrict__ K2,   // [B,128,64]
                                  float* __restrict__ V2,   // [B,128,64]
                                  float* __restrict__ out)  // [B,129,64]
{
    const int blk  = blockIdx.x;
    const int b    = blk >> 7;
    const int q    = blk & 127;
    const int lane = threadIdx.x;
    const int s = lane >> 4, t = lane & 15;

    __shared__ __align__(16) float sc[132];
    __shared__ __align__(16) float av[EE];
    __shared__ __align__(16) float resrow[EE];

    // Q fragment: channels 4t..4t+3 (same for all s groups)
    const float4 q4 = ((const float4*)(Qb + ((long)b * MM + q) * EE))[t];

    // Scores: 4 keys per iter (j = 4*it + s), coalesced float4 K reads.
    const float* Kbase = Kb + (long)b * 129 * EE;
    float mx = -1e30f;
#pragma unroll 4
    for (int it = 0; it < 33; ++it) {
        const int j = it * 4 + s;
        const bool valid = (j < 129);
        float p = 0.0f;
        if (valid) {
            const float4 k4 = ((const float4*)(Kbase + (long)j * EE))[t];
            p = q4.x * k4.x + q4.y * k4.y + q4.z * k4.z + q4.w * k4.w;
        }
        p += __shfl_xor(p, 1); p += __shfl_xor(p, 2);
        p += __shfl_xor(p, 4); p += __shfl_xor(p, 8);
        if (valid) {
            mx = fmaxf(mx, p);
            if (t == 0) sc[j] = p;
        }
    }
#pragma unroll
    for (int off = 32; off >= 1; off >>= 1) mx = fmaxf(mx, __shfl_xor(mx, off));
    __syncthreads();

    float sum = 0.0f;
    for (int j = lane; j < 129; j += 64) {
        const float e = __expf(sc[j] - mx);
        sc[j] = e;
        sum += e;
    }
#pragma unroll
    for (int off = 32; off >= 1; off >>= 1) sum += __shfl_xor(sum, off);
    const float inv = 1.0f / sum;
    __syncthreads();

    // PV: coalesced V reads, 4 independent accumulator chains.
    const float* Vbase = Vb + (long)b * 129 * EE;
    float a0 = 0.f, a1 = 0.f, a2 = 0.f, a3 = 0.f;
#pragma unroll 4
    for (int j0 = 0; j0 < 128; j0 += 4) {
        const float4 s4 = *(const float4*)&sc[j0];
        a0 = fmaf(s4.x, Vbase[(long)(j0 + 0) * EE + lane], a0);
        a1 = fmaf(s4.y, Vbase[(long)(j0 + 1) * EE + lane], a1);
        a2 = fmaf(s4.z, Vbase[(long)(j0 + 2) * EE + lane], a2);
        a3 = fmaf(s4.w, Vbase[(long)(j0 + 3) * EE + lane], a3);
    }
    a0 = fmaf(sc[128], Vbase[(long)128 * EE + lane], a0);
    const float acc = ((a0 + a1) + (a2 + a3)) * inv;
    av[lane] = acc;
    __syncthreads();

    // Output projection + residual
    const float4 o4 = matvec64(Wo, av, s, t);
    const float4 bo4 = ((const float4*)bo)[t];
    const float4 x4 = ((const float4*)(map_emb + ((long)b * MM + q) * EE))[t];
    float4 res;
    res.x = o4.x + bo4.x + x4.x;
    res.y = o4.y + bo4.y + x4.y;
    res.z = o4.z + bo4.z + x4.z;
    res.w = o4.w + bo4.w + x4.w;
    if (s == 0) {
        ((float4*)(out + ((long)b * 129 + 1 + q) * EE))[t] = res;
        ((float4*)resrow)[t] = res;
    }
    __syncthreads();

    // Fused K2/V2 projection of the result row
    const float4 k4 = matvec64(Wk2, resrow, s, t);
    const float4 v4 = matvec64(Wv2, resrow, s, t);
    if (s == 0) {
        const float4 kb4 = ((const float4*)bk2)[t];
        const float4 vb4 = ((const float4*)bv2)[t];
        float4 ko, vo;
        ko.x = k4.x + kb4.x; ko.y = k4.y + kb4.y; ko.z = k4.z + kb4.z; ko.w = k4.w + kb4.w;
        vo.x = v4.x + vb4.x; vo.y = v4.y + vb4.y; vo.z = v4.z + vb4.z; vo.w = v4.w + vb4.w;
        ((float4*)(K2 + ((long)b * MM + q) * EE))[t] = ko;
        ((float4*)(V2 + ((long)b * MM + q) * EE))[t] = vo;
    }
}

// ---------------------------------------------------------------------------
// Target row: t_a (exact single-token shortcut) + t_m2a attention over 128
// map tokens. One block (1 wave) per batch. Writes d_out row 0.
// ---------------------------------------------------------------------------
__global__ void target_kernel(const float* __restrict__ target,
                              const float* __restrict__ K2, const float* __restrict__ V2,
                              const float* __restrict__ Wq2, const float* __restrict__ bq2,
                              const float* __restrict__ Wo2, const float* __restrict__ bo2,
                              const float* __restrict__ Wv1, const float* __restrict__ bv1,
                              const float* __restrict__ Wo1, const float* __restrict__ bo1,
                              float* __restrict__ out)
{
    const int b    = blockIdx.x;
    const int lane = threadIdx.x;
    const int s = lane >> 4, t = lane & 15;

    __shared__ __align__(16) float trow[EE];
    __shared__ __align__(16) float tmp[EE];
    __shared__ __align__(16) float sc[128];
    __shared__ __align__(16) float av[EE];

    trow[lane] = target[(long)b * EE + lane];
    __syncthreads();

    // t_a = (t @ Wv1 + bv1) @ Wo1 + bo1  (softmax over one key == 1)
    const float4 v1 = matvec64(Wv1, trow, s, t);
    if (s == 0) {
        const float4 bv4 = ((const float4*)bv1)[t];
        float4 w; w.x = v1.x + bv4.x; w.y = v1.y + bv4.y; w.z = v1.z + bv4.z; w.w = v1.w + bv4.w;
        ((float4*)tmp)[t] = w;
    }
    __syncthreads();
    float4 ta = matvec64(Wo1, tmp, s, t);
    {
        const float4 bo4 = ((const float4*)bo1)[t];
        ta.x += bo4.x; ta.y += bo4.y; ta.z += bo4.z; ta.w += bo4.w;
    }

    // t_m2a query (pre-scaled)
    float4 q4 = matvec64(Wq2, trow, s, t);
    {
        const float4 bq4 = ((const float4*)bq2)[t];
        q4.x = (q4.x + bq4.x) * 0.125f;
        q4.y = (q4.y + bq4.y) * 0.125f;
        q4.z = (q4.z + bq4.z) * 0.125f;
        q4.w = (q4.w + bq4.w) * 0.125f;
    }

    const float* Kbase = K2 + (long)b * MM * EE;
    float mx = -1e30f;
#pragma unroll 4
    for (int it = 0; it < 32; ++it) {
        const int j = it * 4 + s;
        const float4 k4 = ((const float4*)(Kbase + (long)j * EE))[t];
        float p = q4.x * k4.x + q4.y * k4.y + q4.z * k4.z + q4.w * k4.w;
        p += __shfl_xor(p, 1); p += __shfl_xor(p, 2);
        p += __shfl_xor(p, 4); p += __shfl_xor(p, 8);
        mx = fmaxf(mx, p);
        if (t == 0) sc[j] = p;
    }
#pragma unroll
    for (int off = 32; off >= 1; off >>= 1) mx = fmaxf(mx, __shfl_xor(mx, off));
    __syncthreads();

    float sum = 0.0f;
#pragma unroll
    for (int j = lane; j < MM; j += 64) {
        const float e = __expf(sc[j] - mx);
        sc[j] = e;
        sum += e;
    }
#pragma unroll
    for (int off = 32; off >= 1; off >>= 1) sum += __shfl_xor(sum, off);
    const float inv = 1.0f / sum;
    __syncthreads();

    const float* Vbase = V2 + (long)b * MM * EE;
    float a0 = 0.f, a1 = 0.f, a2 = 0.f, a3 = 0.f;
#pragma unroll 4
    for (int j0 = 0; j0 < 128; j0 += 4) {
        const float4 s4 = *(const float4*)&sc[j0];
        a0 = fmaf(s4.x, Vbase[(long)(j0 + 0) * EE + lane], a0);
        a1 = fmaf(s4.y, Vbase[(long)(j0 + 1) * EE + lane], a1);
        a2 = fmaf(s4.z, Vbase[(long)(j0 + 2) * EE + lane], a2);
        a3 = fmaf(s4.w, Vbase[(long)(j0 + 3) * EE + lane], a3);
    }
    av[lane] = ((a0 + a1) + (a2 + a3)) * inv;
    __syncthreads();

    const float4 o4 = matvec64(Wo2, av, s, t);
    if (s == 0) {
        const float4 bo4 = ((const float4*)bo2)[t];
        float4 r;
        r.x = ta.x + o4.x + bo4.x;
        r.y = ta.y + o4.y + bo4.y;
        r.z = ta.z + o4.z + bo4.z;
        r.w = ta.w + o4.w + bo4.w;
        ((float4*)(out + (long)b * 129 * EE))[t] = r;
    }
}

// ---------------------------------------------------------------------------
extern "C" void kernel_launch(void* const* d_in, const int* in_sizes, int n_in,
                              void* d_out, int out_size, void* d_ws, size_t ws_size,
                              hipStream_t stream)
{
    const float* map_states   = (const float*)d_in[0];
    const float* agent_states = (const float*)d_in[1];
    const float* m_W1 = (const float*)d_in[2];
    const float* m_b1 = (const float*)d_in[3];
    const float* m_g1 = (const float*)d_in[4];
    const float* m_be1 = (const float*)d_in[5];
    const float* m_W2 = (const float*)d_in[6];
    const float* m_b2 = (const float*)d_in[7];
    const float* m_g2 = (const float*)d_in[8];
    const float* m_be2 = (const float*)d_in[9];
    const float* a_W1 = (const float*)d_in[10];
    const float* a_b1 = (const float*)d_in[11];
    const float* a_g1 = (const float*)d_in[12];
    const float* a_be1 = (const float*)d_in[13];
    const float* a_W2 = (const float*)d_in[14];
    const float* a_b2 = (const float*)d_in[15];
    const float* a_g2 = (const float*)d_in[16];
    const float* a_be2 = (const float*)d_in[17];
    const float* att_Wq = (const float*)d_in[18];
    const float* att_bq = (const float*)d_in[19];
    const float* att_Wk = (const float*)d_in[20];
    const float* att_bk = (const float*)d_in[21];
    const float* att_Wv = (const float*)d_in[22];
    const float* att_bv = (const float*)d_in[23];
    const float* att_Wo = (const float*)d_in[24];
    const float* att_bo = (const float*)d_in[25];

    float* out = (float*)d_out;

    // ws layout (floats)
    float* ws      = (float*)d_ws;
    float* map_emb = ws;                          // 32*128*64
    float* target  = map_emb + BB * MM * EE;      // 32*64
    float* Qb      = target + BB * EE;            // 32*128*64
    float* Kb      = Qb + BB * MM * EE;           // 32*129*64
    float* Vb      = Kb + BB * 129 * EE;          // 32*129*64
    float* K2      = Vb + BB * 129 * EE;          // 32*128*64
    float* V2      = K2 + BB * MM * EE;           // 32*128*64

    const float* Wq0 = att_Wq + 0 * EE * EE; const float* bq0 = att_bq + 0 * EE;
    const float* Wk0 = att_Wk + 0 * EE * EE; const float* bk0 = att_bk + 0 * EE;
    const float* Wv0 = att_Wv + 0 * EE * EE; const float* bv0 = att_bv + 0 * EE;
    const float* Wo0 = att_Wo + 0 * EE * EE; const float* bo0 = att_bo + 0 * EE;
    const float* Wv1 = att_Wv + 1 * EE * EE; const float* bv1 = att_bv + 1 * EE;
    const float* Wo1 = att_Wo + 1 * EE * EE; const float* bo1 = att_bo + 1 * EE;
    const float* Wq2 = att_Wq + 2 * EE * EE; const float* bq2 = att_bq + 2 * EE;
    const float* Wk2 = att_Wk + 2 * EE * EE; const float* bk2 = att_bk + 2 * EE;
    const float* Wv2 = att_Wv + 2 * EE * EE; const float* bv2 = att_bv + 2 * EE;
    const float* Wo2 = att_Wo + 2 * EE * EE; const float* bo2 = att_bo + 2 * EE;

    // 1. fused local graphs + QKV projections (map: 4096 blocks, agent: 32)
    hipLaunchKernelGGL(lg_qkv_kernel, dim3(BB * MM + BB), dim3(128), 0, stream,
                       map_states, agent_states,
                       m_W1, m_b1, m_g1, m_be1, m_W2, m_b2, m_g2, m_be2,
                       a_W1, a_b1, a_g1, a_be1, a_W2, a_b2, a_g2, a_be2,
                       Wq0, bq0, Wk0, bk0, Wv0, bv0,
                       map_emb, target, Qb, Kb, Vb);

    // 2. a2m attention + residual + fused K2/V2
    hipLaunchKernelGGL(attn_fused_kernel, dim3(BB * MM), dim3(64), 0, stream,
                       map_emb, Qb, Kb, Vb, Wo0, bo0,
                       Wk2, bk2, Wv2, bv2, K2, V2, out);

    // 3. target row
    hipLaunchKernelGGL(target_kernel, dim3(BB), dim3(64), 0, stream,
                       target, K2, V2, Wq2, bq2, Wo2, bo2, Wv1, bv1, Wo1, bo1, out);
}